// Round 14
// baseline (76.081 us; speedup 1.0000x reference)
//
#include <hip/hip_runtime.h>
#include <hip/hip_bf16.h>
#include <math.h>

#define BATCH 4096
#define NROWS 8192
#define DIM 256
#define NRB 64                        // 128-row panels
#define NCS 16                        // 512-col strips
#define ROWS_PER_BLOCK 128

// zn scale c with c^2 = 2*log2(e): sim_scaled = c^2*cos = 2*log2e*cos,
// so exp2(sim_scaled) = e^{2 cos} directly.
#define ZN_SCALE 1.698643600577466f   // sqrt(2.8853900817779268)
#define LN2F 0.6931471805599453f

typedef __attribute__((ext_vector_type(4))) float f32x4;
typedef __attribute__((ext_vector_type(8))) short short8;

#if defined(__has_builtin)
#if __has_builtin(__builtin_amdgcn_exp2f)
#define EXP2F(x) __builtin_amdgcn_exp2f(x)
#endif
#endif
#ifndef EXP2F
#define EXP2F(x) __expf(LN2F * (x))
#endif

static __device__ __forceinline__ unsigned short f2bf(float x) {
    __hip_bfloat16 h = __float2bfloat16(x);
    return *reinterpret_cast<unsigned short*>(&h);
}
static __device__ __forceinline__ float bf2f(unsigned short u) {
    union { unsigned int i; float f; } x;
    x.i = ((unsigned int)u) << 16;
    return x.f;
}

// ---------------------------------------------------------------------------
// Kernel A: concat + L2-normalize + scale, write row-major (zn) AND
// MFMA-fragment-packed (pk) layouts (R4-proven).
// pk: element (row r, dim e) at granule g*8 + (e&7), where
//     g = ((r>>4)*8 + (e>>5))*64 + ((e&31)>>3)*16 + (r&15)
// ---------------------------------------------------------------------------
__global__ void normalize_kernel(const float* __restrict__ z_i,
                                 const float* __restrict__ z_j,
                                 unsigned short* __restrict__ zn,
                                 unsigned short* __restrict__ pk) {
    int wid  = (blockIdx.x * blockDim.x + threadIdx.x) >> 6;   // row
    int lane = threadIdx.x & 63;
    if (wid >= NROWS) return;
    const float* src = (wid < BATCH) ? (z_i + (size_t)wid * DIM)
                                     : (z_j + (size_t)(wid - BATCH) * DIM);
    float4 v = reinterpret_cast<const float4*>(src)[lane];
    float ss = v.x * v.x + v.y * v.y + v.z * v.z + v.w * v.w;
#pragma unroll
    for (int m = 1; m < 64; m <<= 1) ss += __shfl_xor(ss, m);
    float inv = ZN_SCALE / fmaxf(sqrtf(ss), 1e-8f);
    ushort4 o;
    o.x = f2bf(v.x * inv);
    o.y = f2bf(v.y * inv);
    o.z = f2bf(v.z * inv);
    o.w = f2bf(v.w * inv);
    reinterpret_cast<ushort4*>(zn + (size_t)wid * DIM)[lane] = o;
    size_t g = ((size_t)(wid >> 4) * 8 + (lane >> 3)) * 64
             + ((lane & 7) >> 1) * 16 + (wid & 15);
    *reinterpret_cast<ushort4*>(pk + g * 8 + (lane & 1) * 4) = o;
}

// ---------------------------------------------------------------------------
// Kernel B: R4's measured LDS pipeline, upper-triangle strips only.
// Grid 1024 = (rb: 0..63) x (cs: 0..15); blocks with cs < rb>>2 exit
// immediately (uniform, before any barrier). 544 working blocks.
// Block tile: 128 rows x 512 cols, 16 K-steps (4 col-tiles x BK=64),
// A+B staged via global_load_lds, double-buffered 64 KB, vmcnt(8).
// Wave (wr,wc) owns the 64x64 quadrant of each 128-col tile.
// Crossing strips (rb>>2==cs): elementwise strict col>row mask.
//   col pieces: part_col[rb*2+wr][col]  (wr-banked: NO cross-wave collision)
//   row pieces: part_row[cs*2+wc][row]  (accumulated across 4 col-tiles)
// Coverage for row r: col pieces give sum over rho<r of e(rho,r); row
// pieces give sum over c>r of e(r,c). Diagonal excluded by strict mask.
// ---------------------------------------------------------------------------
typedef const __attribute__((address_space(1))) unsigned int g_u32;
typedef __attribute__((address_space(3))) unsigned int l_u32;

__device__ __forceinline__ void stage_step(const char* __restrict__ pkb,
                                           char* lds, int wave, int lane,
                                           int rb, int cs, int s, int buf) {
    int ct = s >> 2, ks = s & 3;
#pragma unroll
    for (int i = 0; i < 8; ++i) {
        int id  = wave * 8 + i;
        int isB = id >> 4;               // waves 0,1 stage A; 2,3 stage B
        int rtl = (id >> 1) & 7;         // local row-tile 0..7
        int kf  = id & 1;                // k-frag within BK=64
        int rtbase = isB ? (cs * 32 + ct * 8) : (rb * 8);
        size_t grow = (size_t)(rtbase + rtl) * 8 + ks * 2 + kf;
        const char* src = pkb + grow * 1024 + (size_t)lane * 16;
        char* dst = lds + buf * 32768 + isB * 16384 + (rtl * 2 + kf) * 1024;
        __builtin_amdgcn_global_load_lds((g_u32*)src, (l_u32*)dst, 16, 0, 0);
    }
}

__global__ __launch_bounds__(256, 2)
void simloss_kernel(const unsigned short* __restrict__ pk,
                    float* __restrict__ part_col /* [NRB][2][NROWS] */,
                    float* __restrict__ part_row /* [2*NCS][NROWS]  */) {
    __shared__ __attribute__((aligned(16))) unsigned char lds[65536];
    int wave = threadIdx.x >> 6;
    int lane = threadIdx.x & 63;
    int lr = lane & 15;                  // fragment col
    int lk = lane >> 4;                  // fragment row group
    int rb = blockIdx.x & 63;
    int cs = blockIdx.x >> 6;
    if (cs < (rb >> 2)) return;          // lower-triangle strip: block exits
    bool crossing = (cs == (rb >> 2));   // strip contains the diagonal
    int wr = wave >> 1, wc = wave & 1;
    int wr4 = wr * 4, wc4 = wc * 4;
    int R0 = rb * ROWS_PER_BLOCK + wr * 64;
    const char* pkb = (const char*)pk;

    f32x4 acc[4][4];
#pragma unroll
    for (int m = 0; m < 4; ++m)
#pragma unroll
        for (int n = 0; n < 4; ++n) acc[m][n] = (f32x4){0.f, 0.f, 0.f, 0.f};
    float dacc[4][4];
#pragma unroll
    for (int m = 0; m < 4; ++m)
#pragma unroll
        for (int j = 0; j < 4; ++j) dacc[m][j] = 0.f;

    stage_step(pkb, (char*)lds, wave, lane, rb, cs, 0, 0);

#pragma unroll 1
    for (int s = 0; s < 16; ++s) {
        int buf = s & 1;
        if (s < 15) {
            stage_step(pkb, (char*)lds, wave, lane, rb, cs, s + 1, buf ^ 1);
            asm volatile("s_waitcnt vmcnt(8)" ::: "memory");
        } else {
            asm volatile("s_waitcnt vmcnt(0)" ::: "memory");
        }
        __builtin_amdgcn_s_barrier();

        const unsigned short* Ab = (const unsigned short*)(lds + buf * 32768);
        const unsigned short* Bb = (const unsigned short*)(lds + buf * 32768 + 16384);
#pragma unroll
        for (int kf = 0; kf < 2; ++kf) {
            short8 a[4], b[4];
#pragma unroll
            for (int m = 0; m < 4; ++m)
                a[m] = *(const short8*)(Ab + ((wr4 + m) * 2 + kf) * 512 + lane * 8);
#pragma unroll
            for (int n = 0; n < 4; ++n)
                b[n] = *(const short8*)(Bb + ((wc4 + n) * 2 + kf) * 512 + lane * 8);
#pragma unroll
            for (int m = 0; m < 4; ++m)
#pragma unroll
                for (int n = 0; n < 4; ++n)
                    acc[m][n] = __builtin_amdgcn_mfma_f32_16x16x32_bf16(
                        a[m], b[n], acc[m][n], 0, 0, 0);
        }

        if ((s & 3) == 3) {              // col-tile finished: exp2 epilogue
            int ct = s >> 2;
            int Ct = cs * 512 + ct * 128 + wc * 64;    // wave's col base
            float caccT[4] = {0.f, 0.f, 0.f, 0.f};
#pragma unroll
            for (int m = 0; m < 4; ++m) {
#pragma unroll
                for (int n = 0; n < 4; ++n) {
#pragma unroll
                    for (int j = 0; j < 4; ++j) {
                        float e = EXP2F(acc[m][n][j]);
                        if (crossing) {
                            int col = Ct + n * 16 + lr;
                            int row = R0 + m * 16 + lk * 4 + j;
                            if (col <= row) e = 0.0f;   // strict upper only
                        }
                        dacc[m][j] += e;
                        caccT[n] += e;
                    }
                    acc[m][n] = (f32x4){0.f, 0.f, 0.f, 0.f};
                }
            }
            // col pieces for this tile: reduce over the 4 lk row-groups;
            // wr-banked destination -> each wave writes its own slot.
#pragma unroll
            for (int n = 0; n < 4; ++n) {
                float c = caccT[n];
                c += __shfl_xor(c, 16);
                c += __shfl_xor(c, 32);
                if (lk == 0)
                    __builtin_nontemporal_store(c,
                        &part_col[((size_t)rb * 2 + wr) * NROWS + Ct + n * 16 + lr]);
            }
        }
        asm volatile("" ::: "memory");
        __builtin_amdgcn_s_barrier();
    }

    // row pieces: reduce over the 16 col-lanes (lr); lanes lr==0 write
#pragma unroll
    for (int m = 0; m < 4; ++m)
#pragma unroll
        for (int j = 0; j < 4; ++j) {
            float v = dacc[m][j];
            v += __shfl_xor(v, 1);
            v += __shfl_xor(v, 2);
            v += __shfl_xor(v, 4);
            v += __shfl_xor(v, 8);
            if (lr == 0)
                __builtin_nontemporal_store(v,
                    &part_row[(size_t)(cs * 2 + wc) * NROWS
                              + R0 + m * 16 + lk * 4 + j]);
        }
}

// ---------------------------------------------------------------------------
// Kernel C1: positive-pair dots. One row per wave, coalesced zn reads.
// pdot[r] = zn[r].zn[r^BATCH]  (scaled: 2*cos = pdot*ln2)
// ---------------------------------------------------------------------------
__global__ void posdot_kernel(const unsigned short* __restrict__ zn,
                              float* __restrict__ pdot /* [NROWS] */) {
    int wave = threadIdx.x >> 6;
    int lane = threadIdx.x & 63;
    int r = blockIdx.x * 4 + wave;
    ushort4 za = reinterpret_cast<const ushort4*>(zn + (size_t)r * DIM)[lane];
    ushort4 zb = reinterpret_cast<const ushort4*>(zn + (size_t)(r ^ BATCH) * DIM)[lane];
    float dot = bf2f(za.x) * bf2f(zb.x) + bf2f(za.y) * bf2f(zb.y) +
                bf2f(za.z) * bf2f(zb.z) + bf2f(za.w) * bf2f(zb.w);
#pragma unroll
    for (int m = 1; m < 64; m <<= 1) dot += __shfl_xor(dot, m);
    if (lane == 0) pdot[r] = dot;
}

// ---------------------------------------------------------------------------
// Kernel C2: per-row loss, coalesced piece gather. Thread t owns row
// r = blk*256+t; every piece load is a fully-coalesced 1 KB block access.
// Row r (ps = r>>9): col pieces rb in [0, 4ps+4) x {wr0,wr1};
//                    row pieces ids [2ps, 32).
// ---------------------------------------------------------------------------
__global__ void rowsum_kernel(const float* __restrict__ part_col,
                              const float* __restrict__ part_row,
                              const float* __restrict__ pdot,
                              float* __restrict__ cpart /* [32] */) {
    int tid = threadIdx.x;
    int r = blockIdx.x * 256 + tid;
    int ps = r >> 9;                     // uniform across the block
    float den = 0.f;
    int nbank = 2 * (4 * ps + 4);        // wr-banked col pieces
#pragma unroll 4
    for (int id = 0; id < nbank; ++id)
        den += part_col[(size_t)id * NROWS + r];
#pragma unroll 4
    for (int id = 2 * ps; id < 2 * NCS; ++id)
        den += part_row[(size_t)id * NROWS + r];
    float loss = logf(den) - pdot[r] * LN2F;
    // block reduce
    int lane = tid & 63, wave = tid >> 6;
#pragma unroll
    for (int m = 1; m < 64; m <<= 1) loss += __shfl_xor(loss, m);
    __shared__ float red[4];
    if (lane == 0) red[wave] = loss;
    __syncthreads();
    if (tid == 0) cpart[blockIdx.x] = red[0] + red[1] + red[2] + red[3];
}

// ---------------------------------------------------------------------------
// Kernel D: final reduction of 32 block partials -> scalar loss / n
// ---------------------------------------------------------------------------
__global__ void final_kernel(const float* __restrict__ cpart,
                             float* __restrict__ out) {
    int lane = threadIdx.x & 63;
    double v = (lane < 32) ? (double)cpart[lane] : 0.0;
#pragma unroll
    for (int m = 1; m < 64; m <<= 1) v += __shfl_xor(v, m);
    if (lane == 0) out[0] = (float)(v / (double)NROWS);
}

// ---------------------------------------------------------------------------
extern "C" void kernel_launch(void* const* d_in, const int* in_sizes, int n_in,
                              void* d_out, int out_size, void* d_ws, size_t ws_size,
                              hipStream_t stream) {
    const float* z_i = (const float*)d_in[0];
    const float* z_j = (const float*)d_in[1];
    float* out = (float*)d_out;
    char* ws = (char*)d_ws;

    unsigned short* zn = (unsigned short*)ws;                              // 4 MB
    unsigned short* pk = (unsigned short*)(ws + (size_t)NROWS * DIM * 2);  // 4 MB
    float* part_col = (float*)(ws + 2 * (size_t)NROWS * DIM * 2);          // 4 MB
    float* part_row = (float*)(ws + 2 * (size_t)NROWS * DIM * 2
                                  + (size_t)NRB * 2 * NROWS * 4);          // 1 MB
    float* pdot  = (float*)(ws + 2 * (size_t)NROWS * DIM * 2
                               + (size_t)(2 * NRB + 2 * NCS) * NROWS * 4); // 32 KB
    float* cpart = pdot + NROWS;                                           // 128 B

    normalize_kernel<<<NROWS / 4, 256, 0, stream>>>(z_i, z_j, zn, pk);
    simloss_kernel<<<NRB * NCS, 256, 0, stream>>>(pk, part_col, part_row);
    posdot_kernel<<<NROWS / 4, 256, 0, stream>>>(zn, pdot);
    rowsum_kernel<<<NROWS / 256, 256, 0, stream>>>(part_col, part_row, pdot, cpart);
    final_kernel<<<1, 64, 0, stream>>>(cpart, out);
}

// Round 16
// 45.353 us; speedup vs baseline: 1.6775x; 1.6775x over previous
//
#include <hip/hip_runtime.h>
#include <hip/hip_bf16.h>
#include <hip/hip_fp8.h>
#include <math.h>

#define BATCH 4096
#define NROWS 8192
#define DIM 256
#define NP 64                         // 128-row panels
#define NBLK (NP * (NP + 1) / 2)      // 2080 upper-triangle tiles
#define NPIECE (2 * NP)               // 128 denominator pieces per row

// zn scale c with c^2 = 2*log2(e): sim_scaled = c^2*cos = 2*log2e*cos,
// so exp2(sim_scaled) = e^{2 cos} directly. (e4m3 is a float format ->
// relative precision is scale-invariant.)
#define ZN_SCALE 1.698643600577466f   // sqrt(2.8853900817779268)
#define LN2F 0.6931471805599453f

typedef __attribute__((ext_vector_type(4))) float f32x4;

#if defined(__has_builtin)
#if __has_builtin(__builtin_amdgcn_exp2f)
#define EXP2F(x) __builtin_amdgcn_exp2f(x)
#endif
#endif
#ifndef EXP2F
#define EXP2F(x) __expf(LN2F * (x))
#endif

static __device__ __forceinline__ unsigned short f2bf(float x) {
    __hip_bfloat16 h = __float2bfloat16(x);
    return *reinterpret_cast<unsigned short*>(&h);
}
static __device__ __forceinline__ float bf2f(unsigned short u) {
    union { unsigned int i; float f; } x;
    x.i = ((unsigned int)u) << 16;
    return x.f;
}
static __device__ __forceinline__ unsigned char f2fp8(float x) {
    __hip_fp8_e4m3 h(x);              // OCP e4m3fn (gfx950)
    return *reinterpret_cast<unsigned char*>(&h);
}

// ---------------------------------------------------------------------------
// Kernel A (R12-proven): concat + L2-normalize + scale; write row-major bf16
// (zn, for the positive-pair dot) AND fp8-e4m3 fragment-packed (pk8).
// pk8 granule = one (16-row x 32-k) fp8 fragment = 512 B, lane order for
// v_mfma_f32_16x16x32_fp8_fp8. Row-tile rt (16 rows) = 8 granules = 4 KB,
// contiguous; a 128-row panel = 32 KB contiguous.
// ---------------------------------------------------------------------------
__global__ void normalize_kernel(const float* __restrict__ z_i,
                                 const float* __restrict__ z_j,
                                 unsigned short* __restrict__ zn,
                                 unsigned char* __restrict__ pk8) {
    int wid  = (blockIdx.x * blockDim.x + threadIdx.x) >> 6;   // row
    int lane = threadIdx.x & 63;
    if (wid >= NROWS) return;
    const float* src = (wid < BATCH) ? (z_i + (size_t)wid * DIM)
                                     : (z_j + (size_t)(wid - BATCH) * DIM);
    float4 v = reinterpret_cast<const float4*>(src)[lane];
    float ss = v.x * v.x + v.y * v.y + v.z * v.z + v.w * v.w;
#pragma unroll
    for (int m = 1; m < 64; m <<= 1) ss += __shfl_xor(ss, m);
    float inv = ZN_SCALE / fmaxf(sqrtf(ss), 1e-8f);
    ushort4 o;
    o.x = f2bf(v.x * inv);
    o.y = f2bf(v.y * inv);
    o.z = f2bf(v.z * inv);
    o.w = f2bf(v.w * inv);
    reinterpret_cast<ushort4*>(zn + (size_t)wid * DIM)[lane] = o;
    uchar4 o8;
    o8.x = f2fp8(v.x * inv);
    o8.y = f2fp8(v.y * inv);
    o8.z = f2fp8(v.z * inv);
    o8.w = f2fp8(v.w * inv);
    size_t off8 = ((size_t)(wid >> 4) * 8 + (lane >> 3)) * 512
                + (size_t)(((lane & 7) >> 1) * 16 + (wid & 15)) * 8
                + (size_t)(lane & 1) * 4;
    *reinterpret_cast<uchar4*>(pk8 + off8) = o8;
}

// ---------------------------------------------------------------------------
// Kernel B: symmetric fused sim-GEMM + sum-of-exp — fp8, A-in-registers,
// B-in-LDS (staged ONCE per tile), ONE barrier per tile.
// Grid 2080 = upper-triangle (p,q) 128x128 tiles, XCD swizzle 8x260
// (bijective: 2080 = 8*260). Block = 4 waves (2x2); wave = 64x64 quadrant.
// Per tile: B panel q = contiguous 32 KB of pk8 -> linear global_load_lds;
// A panel rows for this wave = 32 frags x 8 B -> 64 VGPRs, loaded once.
// K-loop: 8 slices of {4x ds_read_b64 + 16 MFMA}; no barriers, no vmcnt.
// Epilogue + piece scheme = R12 verbatim (measured absmax 0):
//   row pieces: part[q*2+wc][rows of panel p]   (all tiles)
//   col pieces: part[p*2+wr][cols of panel q]   (p!=q, symmetry)
// Row r (panel pr) coverage: ids [2pr,128) row + ids [0,2pr) col = all 128.
// ---------------------------------------------------------------------------
typedef const __attribute__((address_space(1))) unsigned int g_u32;
typedef __attribute__((address_space(3))) unsigned int l_u32;

__device__ __forceinline__ void unrank_tile(int t, int& p, int& q) {
    int pp = (int)((129.0f - sqrtf(16641.0f - 8.0f * (float)t)) * 0.5f);
    pp = pp < 0 ? 0 : (pp > 63 ? 63 : pp);
    while (pp > 0 && t < pp * (129 - pp) / 2) --pp;
    while (pp < 63 && t >= (pp + 1) * (128 - pp) / 2) ++pp;
    p = pp;
    q = pp + (t - pp * (129 - pp) / 2);
}

__global__ __launch_bounds__(256, 3)
void simloss_kernel(const unsigned char* __restrict__ pk8,
                    float* __restrict__ part /* [NPIECE][NROWS] */) {
    __shared__ __attribute__((aligned(16))) unsigned char ldsB[32768];
    int wave = threadIdx.x >> 6;
    int lane = threadIdx.x & 63;
    int lr = lane & 15;                  // fragment col
    int lk = lane >> 4;                  // fragment row group
    int wr = wave >> 1, wc = wave & 1;
    // XCD-contiguous bijective swizzle: 2080 = 8 x 260
    int bt = (int)blockIdx.x;
    int t = (bt & 7) * 260 + (bt >> 3);
    int p, q;
    unrank_tile(t, p, q);

    const char* pkb = (const char*)pk8;

    // --- stage B panel q: contiguous 32 KB, 8 chunks of 1 KB per wave ---
#pragma unroll
    for (int i = 0; i < 8; ++i) {
        int chunk = wave * 8 + i;        // 0..31
        const char* src = pkb + (size_t)q * 32768 + (size_t)chunk * 1024
                        + (size_t)lane * 16;
        char* dst = (char*)ldsB + chunk * 1024;
        __builtin_amdgcn_global_load_lds((g_u32*)src, (l_u32*)dst, 16, 0, 0);
    }

    // --- A fragments into registers: 4 row-tiles x 8 slices (64 VGPR) ---
    const char* Abase = pkb + (size_t)(p * 8 + wr * 4) * 4096 + (size_t)lane * 8;
    long long Ar[4][8];
#pragma unroll
    for (int m = 0; m < 4; ++m)
#pragma unroll
        for (int s = 0; s < 8; ++s)
            Ar[m][s] = *(const long long*)(Abase + m * 4096 + s * 512);

    f32x4 acc[4][4];
#pragma unroll
    for (int m = 0; m < 4; ++m)
#pragma unroll
        for (int n = 0; n < 4; ++n) acc[m][n] = (f32x4){0.f, 0.f, 0.f, 0.f};

    __syncthreads();                     // waits vmcnt(0) + lgkmcnt(0)

    // --- K-loop: pure LDS reads + MFMA, no barriers ---
    const char* Bb = (const char*)ldsB + (size_t)(wc * 4) * 4096
                   + (size_t)lane * 8;
#pragma unroll
    for (int s = 0; s < 8; ++s) {
        long long Bf[4];
#pragma unroll
        for (int n = 0; n < 4; ++n)
            Bf[n] = *(const long long*)(Bb + n * 4096 + s * 512);
#pragma unroll
        for (int m = 0; m < 4; ++m)
#pragma unroll
            for (int n = 0; n < 4; ++n)
                acc[m][n] = __builtin_amdgcn_mfma_f32_16x16x32_fp8_fp8(
                    Ar[m][s], Bf[n], acc[m][n], 0, 0, 0);
    }

    // ---- epilogue (R12 verbatim): exp2, diag-zero, row + col sums ----
    int R0 = p * 128 + wr * 64;
    int C0 = q * 128 + wc * 64;
    float dacc[4][4];
#pragma unroll
    for (int m = 0; m < 4; ++m)
#pragma unroll
        for (int j = 0; j < 4; ++j) dacc[m][j] = 0.f;
    float cacc[4] = {0.f, 0.f, 0.f, 0.f};

#pragma unroll
    for (int m = 0; m < 4; ++m) {
        int gr = R0 + m * 16;
#pragma unroll
        for (int n = 0; n < 4; ++n) {
            int gc = C0 + n * 16;
            bool diagf = (gr == gc);      // uniform per fragment
            float cs_ = 0.f;
#pragma unroll
            for (int j = 0; j < 4; ++j) {
                float e = EXP2F(acc[m][n][j]);
                if (diagf && lr == lk * 4 + j) e = 0.0f;
                dacc[m][j] += e;
                cs_ += e;
            }
            cacc[n] += cs_;
        }
    }

    // row pieces: reduce over 16 col-lanes (lr); lanes lr==0 write (nt)
#pragma unroll
    for (int m = 0; m < 4; ++m)
#pragma unroll
        for (int j = 0; j < 4; ++j) {
            float v = dacc[m][j];
            v += __shfl_xor(v, 1);
            v += __shfl_xor(v, 2);
            v += __shfl_xor(v, 4);
            v += __shfl_xor(v, 8);
            if (lr == 0)
                __builtin_nontemporal_store(v,
                    &part[(size_t)(q * 2 + wc) * NROWS + R0 + m * 16 + lk * 4 + j]);
        }
    // col pieces: reduce over the 4 lk groups; lanes lk==0 (0..15) write (nt)
    if (p != q) {
#pragma unroll
        for (int n = 0; n < 4; ++n) {
            float c = cacc[n];
            c += __shfl_xor(c, 16);
            c += __shfl_xor(c, 32);
            if (lk == 0)
                __builtin_nontemporal_store(c,
                    &part[(size_t)(p * 2 + wr) * NROWS + C0 + n * 16 + lr]);
        }
    }
}

// ---------------------------------------------------------------------------
// Kernel C (R12 verbatim): per-row loss: log(sum of 128 pieces) - pos_dot*ln2
// One row per wave; part (4 MB) is L2/L3-resident.
// ---------------------------------------------------------------------------
__global__ void rowloss_kernel(const unsigned short* __restrict__ zn,
                               const float* __restrict__ part,
                               float* __restrict__ cpart /* [NROWS] */) {
    int wave = threadIdx.x >> 6;
    int lane = threadIdx.x & 63;
    int r = blockIdx.x * 4 + wave;
    ushort4 za = reinterpret_cast<const ushort4*>(zn + (size_t)r * DIM)[lane];
    ushort4 zb = reinterpret_cast<const ushort4*>(zn + (size_t)(r ^ BATCH) * DIM)[lane];
    float dot = bf2f(za.x) * bf2f(zb.x) + bf2f(za.y) * bf2f(zb.y) +
                bf2f(za.z) * bf2f(zb.z) + bf2f(za.w) * bf2f(zb.w);
#pragma unroll
    for (int m = 1; m < 64; m <<= 1) dot += __shfl_xor(dot, m);
    float den = part[(size_t)lane * NROWS + r]
              + part[(size_t)(lane + 64) * NROWS + r];
#pragma unroll
    for (int m = 1; m < 64; m <<= 1) den += __shfl_xor(den, m);
    if (lane == 0) cpart[r] = logf(den) - dot * LN2F;
}

// ---------------------------------------------------------------------------
// Kernel D (R12 verbatim): final reduction of 8192 row losses -> loss / n
// ---------------------------------------------------------------------------
__global__ void final_kernel(const float* __restrict__ cpart,
                             float* __restrict__ out) {
    int lane = threadIdx.x & 63;
    int wave = threadIdx.x >> 6;
    double v = 0.0;
#pragma unroll
    for (int k = 0; k < 32; ++k)
        v += (double)cpart[threadIdx.x + k * 256];
#pragma unroll
    for (int m = 1; m < 64; m <<= 1) v += __shfl_xor(v, m);
    __shared__ double red[4];
    if (lane == 0) red[wave] = v;
    __syncthreads();
    if (threadIdx.x == 0)
        out[0] = (float)((red[0] + red[1] + red[2] + red[3]) / (double)NROWS);
}

// ---------------------------------------------------------------------------
extern "C" void kernel_launch(void* const* d_in, const int* in_sizes, int n_in,
                              void* d_out, int out_size, void* d_ws, size_t ws_size,
                              hipStream_t stream) {
    const float* z_i = (const float*)d_in[0];
    const float* z_j = (const float*)d_in[1];
    float* out = (float*)d_out;
    char* ws = (char*)d_ws;

    unsigned short* zn  = (unsigned short*)ws;                             // 4 MB
    unsigned char*  pk8 = (unsigned char*)(ws + (size_t)NROWS * DIM * 2);  // 2 MB
    float* part  = (float*)(ws + (size_t)NROWS * DIM * 2
                               + (size_t)NROWS * DIM);                     // 4 MB
    float* cpart = (float*)(ws + (size_t)NROWS * DIM * 2
                               + (size_t)NROWS * DIM
                               + (size_t)NPIECE * NROWS * 4);              // 32 KB

    normalize_kernel<<<NROWS / 4, 256, 0, stream>>>(z_i, z_j, zn, pk8);
    simloss_kernel<<<NBLK, 256, 0, stream>>>(pk8, part);
    rowloss_kernel<<<NROWS / 4, 256, 0, stream>>>(zn, part, cpart);
    final_kernel<<<1, 256, 0, stream>>>(cpart, out);
}